// Round 13
// baseline (652.474 us; speedup 1.0000x reference)
//
#include <hip/hip_runtime.h>

#define MD 4
#define DD 9          // 2*MD+1
#define KK 81         // DD*DD
#define B_ 4
#define C_ 128
#define H_ 192
#define W_ 192
#define HW (H_ * W_)
#define NWG 1152      // 96 y-pairs * 3 xt * 4 b  (all 128 ch per block)
#define PER_XCD (NWG / 8)

// out[b,c,y,x] = (1/C) * sum_{p,o} first[b,p*9+o,y,x] * second[b,c,y+p-4,x+o-4]
//
// Round 13 = round-12 algorithm, 512-thread blocks.
// r12 post-mortem: dur 85us == VMEM 30 + DS 32 + VALU 22 us SERIALIZED; only
// 3 waves/SIMD (LDS 41.5KB -> 3 blocks/CU x 4 waves) so pipes never overlap.
// Fix: merge the 2 channel-halves into one 512-thread block -> same 41.5KB
// LDS now feeds 8 waves; 3 blocks/CU = 24 waves/CU = 6 waves/SIMD. TLP
// doubles at zero algorithmic cost; target wall = max(32,30,22)+e ~= 40us.
// Thread work identical to r12: 4x * 4ch * 2y, window reuse across y-pair
// (24:1 FMA:load), stage-masked x-edge weights (proven), same accumulation
// order. launch_bounds(512,6): allocator budget 85 >= the 72 this needs.
// Sentinels: Occupancy >= 55% (theory), VGPR in [72,84], WRITE == 73728 KB.

#define FMA16(A0, A1, A2, A3, FO, O)                                   \
  A0[0] = fmaf(FO.x, w0[(O) + 0], A0[0]);                              \
  A0[1] = fmaf(FO.y, w0[(O) + 1], A0[1]);                              \
  A0[2] = fmaf(FO.z, w0[(O) + 2], A0[2]);                              \
  A0[3] = fmaf(FO.w, w0[(O) + 3], A0[3]);                              \
  A1[0] = fmaf(FO.x, w1[(O) + 0], A1[0]);                              \
  A1[1] = fmaf(FO.y, w1[(O) + 1], A1[1]);                              \
  A1[2] = fmaf(FO.z, w1[(O) + 2], A1[2]);                              \
  A1[3] = fmaf(FO.w, w1[(O) + 3], A1[3]);                              \
  A2[0] = fmaf(FO.x, w2[(O) + 0], A2[0]);                              \
  A2[1] = fmaf(FO.y, w2[(O) + 1], A2[1]);                              \
  A2[2] = fmaf(FO.z, w2[(O) + 2], A2[2]);                              \
  A2[3] = fmaf(FO.w, w2[(O) + 3], A2[3]);                              \
  A3[0] = fmaf(FO.x, w3[(O) + 0], A3[0]);                              \
  A3[1] = fmaf(FO.y, w3[(O) + 1], A3[1]);                              \
  A3[2] = fmaf(FO.z, w3[(O) + 2], A3[2]);                              \
  A3[3] = fmaf(FO.w, w3[(O) + 3], A3[3]);

__global__ __launch_bounds__(512, 6)
void corr_transpose_kernel(const float* __restrict__ first,
                           const float* __restrict__ second,
                           float* __restrict__ out) {
  __shared__ __align__(16) float ldsF[2][KK * 64];

  // bijective XCD swizzle (1152 % 8 == 0), y-pair-fastest within an XCD chunk
  const int lin = blockIdx.x;
  const int wid = (lin & 7) * PER_XCD + (lin >> 3);
  const int yp  = wid % 96;
  const int t   = wid / 96;          // 0..11
  const int xt0 = (t % 3) * 64;
  const int b   = t / 3;
  const int y0  = yp * 2;            // output rows y0, y0+1

  const int tid = threadIdx.x;

  // ---- stage first[b,:,y0+slab,xt0..+63] into 2 LDS slabs, edge-masked ----
  const bool edge = (xt0 != 64);     // block-uniform
#pragma unroll
  for (int slab = 0; slab < 2; ++slab) {
    const float* fbase =
        first + ((size_t)(b * KK) * H_ + (y0 + slab)) * (size_t)W_ + xt0;
    for (int idx = tid; idx < KK * 16; idx += 512) {
      const int k  = idx >> 4;
      const int xi = (idx & 15) << 2;
      float4 v = *reinterpret_cast<const float4*>(fbase + (size_t)k * HW + xi);
      if (edge) {
        const int o    = k % DD;
        const int base = xt0 + xi + o - MD;   // second-x for component 0
        if (base + 0 < 0 || base + 0 >= W_) v.x = 0.f;
        if (base + 1 < 0 || base + 1 >= W_) v.y = 0.f;
        if (base + 2 < 0 || base + 2 >= W_) v.z = 0.f;
        if (base + 3 < 0 || base + 3 >= W_) v.w = 0.f;
      }
      *reinterpret_cast<float4*>(&ldsF[slab][k * 64 + xi]) = v;
    }
  }

  const int xg = tid & 15;           // 16 x-groups (vec4)
  const int cg = tid >> 4;           // 0..31, 4 channels each -> 128 ch
  const int c0 = cg * 4;
  const int x0 = xt0 + xg * 4;

  // clamped window offsets; OOB float4s have zeroed weights in LDS
  const bool mA = (x0 != 0);
  const bool mE = (x0 + 8 <= W_);
  const int  oa = mA ? x0 - 4 : 0;
  const int  oe = mE ? x0 + 4 : W_ - 8;

  // row range: yy = y0-4+r, r in [r_lo, r_hi], yy within [0,191]
  const int r_lo = (y0 >= MD) ? 0 : (MD - y0);
  const int r_hi = (195 - y0 < 9) ? (195 - y0) : 9;

  const float* secB = second + (size_t)b * C_ * HW;
  const float* rp0 =
      secB + ((size_t)(c0 + 0) * H_ + (y0 - MD + r_lo)) * (size_t)W_;
  const float* rp1 = rp0 + HW;
  const float* rp2 = rp1 + HW;
  const float* rp3 = rp2 + HW;

  __syncthreads();

  float a00[4] = {0.f, 0.f, 0.f, 0.f};   // dy0, ci=0..3
  float a01[4] = {0.f, 0.f, 0.f, 0.f};
  float a02[4] = {0.f, 0.f, 0.f, 0.f};
  float a03[4] = {0.f, 0.f, 0.f, 0.f};
  float a10[4] = {0.f, 0.f, 0.f, 0.f};   // dy1
  float a11[4] = {0.f, 0.f, 0.f, 0.f};
  float a12[4] = {0.f, 0.f, 0.f, 0.f};
  float a13[4] = {0.f, 0.f, 0.f, 0.f};

  for (int r = r_lo; r <= r_hi; ++r) {
    // windows: second[c0+ci, yy, x0-4 .. x0+7] (12 floats each)
    float w0[12], w1[12], w2[12], w3[12];
    *reinterpret_cast<float4*>(&w0[0]) = *reinterpret_cast<const float4*>(rp0 + oa);
    *reinterpret_cast<float4*>(&w0[4]) = *reinterpret_cast<const float4*>(rp0 + x0);
    *reinterpret_cast<float4*>(&w0[8]) = *reinterpret_cast<const float4*>(rp0 + oe);
    *reinterpret_cast<float4*>(&w1[0]) = *reinterpret_cast<const float4*>(rp1 + oa);
    *reinterpret_cast<float4*>(&w1[4]) = *reinterpret_cast<const float4*>(rp1 + x0);
    *reinterpret_cast<float4*>(&w1[8]) = *reinterpret_cast<const float4*>(rp1 + oe);
    *reinterpret_cast<float4*>(&w2[0]) = *reinterpret_cast<const float4*>(rp2 + oa);
    *reinterpret_cast<float4*>(&w2[4]) = *reinterpret_cast<const float4*>(rp2 + x0);
    *reinterpret_cast<float4*>(&w2[8]) = *reinterpret_cast<const float4*>(rp2 + oe);
    *reinterpret_cast<float4*>(&w3[0]) = *reinterpret_cast<const float4*>(rp3 + oa);
    *reinterpret_cast<float4*>(&w3[4]) = *reinterpret_cast<const float4*>(rp3 + x0);
    *reinterpret_cast<float4*>(&w3[8]) = *reinterpret_cast<const float4*>(rp3 + oe);

    if (r <= 8) {                       // dy=0 contribution, p = r
      const float* fbp = &ldsF[0][(r * DD) * 64 + (xg << 2)];
#pragma unroll
      for (int o = 0; o < DD; ++o) {
        const float4 fo = *reinterpret_cast<const float4*>(fbp + o * 64);
        FMA16(a00, a01, a02, a03, fo, o)
      }
    }
    if (r >= 1) {                       // dy=1 contribution, p = r-1
      const float* fbp = &ldsF[1][((r - 1) * DD) * 64 + (xg << 2)];
#pragma unroll
      for (int o = 0; o < DD; ++o) {
        const float4 fo = *reinterpret_cast<const float4*>(fbp + o * 64);
        FMA16(a10, a11, a12, a13, fo, o)
      }
    }

    rp0 += W_; rp1 += W_; rp2 += W_; rp3 += W_;
  }

  const float inv_c = 1.0f / (float)C_;
  float* ob0 = out + (size_t)b * C_ * HW + (size_t)y0 * W_ + x0;
  float* ob1 = ob0 + W_;
#define STORE4(PTR, CI, ACC)                                              \
  {                                                                       \
    float4 v;                                                             \
    v.x = ACC[0] * inv_c; v.y = ACC[1] * inv_c;                           \
    v.z = ACC[2] * inv_c; v.w = ACC[3] * inv_c;                           \
    *reinterpret_cast<float4*>(PTR + (size_t)(c0 + CI) * HW) = v;         \
  }
  STORE4(ob0, 0, a00)
  STORE4(ob0, 1, a01)
  STORE4(ob0, 2, a02)
  STORE4(ob0, 3, a03)
  STORE4(ob1, 0, a10)
  STORE4(ob1, 1, a11)
  STORE4(ob1, 2, a12)
  STORE4(ob1, 3, a13)
#undef STORE4
}

extern "C" void kernel_launch(void* const* d_in, const int* in_sizes, int n_in,
                              void* d_out, int out_size, void* d_ws, size_t ws_size,
                              hipStream_t stream) {
  const float* first  = (const float*)d_in[0];
  const float* second = (const float*)d_in[1];
  float* out = (float*)d_out;

  corr_transpose_kernel<<<dim3(NWG), 512, 0, stream>>>(first, second, out);
}

// Round 14
// 111.166 us; speedup vs baseline: 5.8694x; 5.8694x over previous
//
#include <hip/hip_runtime.h>

#define MD 4
#define DD 9          // 2*MD+1
#define KK 81         // DD*DD
#define B_ 4
#define C_ 128
#define H_ 192
#define W_ 192
#define HW (H_ * W_)
#define XT 32         // x-tile width
#define NWG 2304      // 96 y-pairs * 6 xt * 4 b  (all 128 ch per block)
#define PER_XCD (NWG / 8)

// out[b,c,y,x] = (1/C) * sum_{p,o} first[b,p*9+o,y,x] * second[b,c,y+p-4,x+o-4]
//
// Round 14 = round-12 algorithm (85.2us best; VMEM+DS+VALU were SERIALIZED at
// 3 waves/SIMD) with HALF the LDS per block: x-tile 32 -> slab pair 20.7KB ->
// 7 blocks/CU = 7 waves/SIMD. Occupancy comes from the LDS denominator, NOT
// from block size / launch-bounds floor: r13's (512,6) hard-capped the
// allocator (VGPR 40, WRITE 1.6GB spill, 652us). Keep (256,2): proven to
// grant ~72 VGPR with zero spill for this exact thread body (r12).
// Thread: 4x * 4ch * 2y; window loads reused across the y-pair (24:1
// FMA:load); weights from LDS (2-way banks, 8-way broadcast); x-edge folded
// into weights at stage time; same accumulation order as reference.
// Sentinels: LDS ~20.7KB, VGPR 64-76, WRITE == 73728 KB exactly,
// Occupancy >= 55%, dur 50-65us.

#define FMA16(A0, A1, A2, A3, FO, O)                                   \
  A0[0] = fmaf(FO.x, w0[(O) + 0], A0[0]);                              \
  A0[1] = fmaf(FO.y, w0[(O) + 1], A0[1]);                              \
  A0[2] = fmaf(FO.z, w0[(O) + 2], A0[2]);                              \
  A0[3] = fmaf(FO.w, w0[(O) + 3], A0[3]);                              \
  A1[0] = fmaf(FO.x, w1[(O) + 0], A1[0]);                              \
  A1[1] = fmaf(FO.y, w1[(O) + 1], A1[1]);                              \
  A1[2] = fmaf(FO.z, w1[(O) + 2], A1[2]);                              \
  A1[3] = fmaf(FO.w, w1[(O) + 3], A1[3]);                              \
  A2[0] = fmaf(FO.x, w2[(O) + 0], A2[0]);                              \
  A2[1] = fmaf(FO.y, w2[(O) + 1], A2[1]);                              \
  A2[2] = fmaf(FO.z, w2[(O) + 2], A2[2]);                              \
  A2[3] = fmaf(FO.w, w2[(O) + 3], A2[3]);                              \
  A3[0] = fmaf(FO.x, w3[(O) + 0], A3[0]);                              \
  A3[1] = fmaf(FO.y, w3[(O) + 1], A3[1]);                              \
  A3[2] = fmaf(FO.z, w3[(O) + 2], A3[2]);                              \
  A3[3] = fmaf(FO.w, w3[(O) + 3], A3[3]);

__global__ __launch_bounds__(256, 2)
void corr_transpose_kernel(const float* __restrict__ first,
                           const float* __restrict__ second,
                           float* __restrict__ out) {
  __shared__ __align__(16) float ldsF[2][KK * XT];

  // bijective XCD swizzle (2304 % 8 == 0), y-pair-fastest within an XCD chunk
  const int lin = blockIdx.x;
  const int wid = (lin & 7) * PER_XCD + (lin >> 3);
  const int yp  = wid % 96;
  const int t   = wid / 96;          // 0..23
  const int xt0 = (t % 6) * XT;
  const int b   = t / 6;
  const int y0  = yp * 2;            // output rows y0, y0+1

  const int tid = threadIdx.x;

  // ---- stage first[b,:,y0+slab,xt0..+31] into 2 LDS slabs, edge-masked ----
  const bool edge = (xt0 == 0) || (xt0 == W_ - XT);   // block-uniform
#pragma unroll
  for (int slab = 0; slab < 2; ++slab) {
    const float* fbase =
        first + ((size_t)(b * KK) * H_ + (y0 + slab)) * (size_t)W_ + xt0;
    for (int idx = tid; idx < KK * (XT / 4); idx += 256) {
      const int k  = idx >> 3;
      const int xi = (idx & 7) << 2;
      float4 v = *reinterpret_cast<const float4*>(fbase + (size_t)k * HW + xi);
      if (edge) {
        const int o    = k % DD;
        const int base = xt0 + xi + o - MD;   // second-x for component 0
        if (base + 0 < 0 || base + 0 >= W_) v.x = 0.f;
        if (base + 1 < 0 || base + 1 >= W_) v.y = 0.f;
        if (base + 2 < 0 || base + 2 >= W_) v.z = 0.f;
        if (base + 3 < 0 || base + 3 >= W_) v.w = 0.f;
      }
      *reinterpret_cast<float4*>(&ldsF[slab][k * XT + xi]) = v;
    }
  }

  const int xg = tid & 7;            // 8 x-groups (vec4)
  const int cg = tid >> 3;           // 0..31, 4 channels each -> 128 ch
  const int c0 = cg * 4;
  const int x0 = xt0 + xg * 4;

  // clamped window offsets; OOB float4s have zeroed weights in LDS
  const bool mA = (x0 != 0);
  const bool mE = (x0 + 8 <= W_);
  const int  oa = mA ? x0 - 4 : 0;
  const int  oe = mE ? x0 + 4 : W_ - 8;

  // row range: yy = y0-4+r, r in [r_lo, r_hi], yy within [0,191]
  const int r_lo = (y0 >= MD) ? 0 : (MD - y0);
  const int r_hi = (195 - y0 < 9) ? (195 - y0) : 9;

  const float* secB = second + (size_t)b * C_ * HW;
  const float* rp0 =
      secB + ((size_t)(c0 + 0) * H_ + (y0 - MD + r_lo)) * (size_t)W_;
  const float* rp1 = rp0 + HW;
  const float* rp2 = rp1 + HW;
  const float* rp3 = rp2 + HW;

  __syncthreads();

  float a00[4] = {0.f, 0.f, 0.f, 0.f};   // dy0, ci=0..3
  float a01[4] = {0.f, 0.f, 0.f, 0.f};
  float a02[4] = {0.f, 0.f, 0.f, 0.f};
  float a03[4] = {0.f, 0.f, 0.f, 0.f};
  float a10[4] = {0.f, 0.f, 0.f, 0.f};   // dy1
  float a11[4] = {0.f, 0.f, 0.f, 0.f};
  float a12[4] = {0.f, 0.f, 0.f, 0.f};
  float a13[4] = {0.f, 0.f, 0.f, 0.f};

  for (int r = r_lo; r <= r_hi; ++r) {
    // windows: second[c0+ci, yy, x0-4 .. x0+7] (12 floats each)
    float w0[12], w1[12], w2[12], w3[12];
    *reinterpret_cast<float4*>(&w0[0]) = *reinterpret_cast<const float4*>(rp0 + oa);
    *reinterpret_cast<float4*>(&w0[4]) = *reinterpret_cast<const float4*>(rp0 + x0);
    *reinterpret_cast<float4*>(&w0[8]) = *reinterpret_cast<const float4*>(rp0 + oe);
    *reinterpret_cast<float4*>(&w1[0]) = *reinterpret_cast<const float4*>(rp1 + oa);
    *reinterpret_cast<float4*>(&w1[4]) = *reinterpret_cast<const float4*>(rp1 + x0);
    *reinterpret_cast<float4*>(&w1[8]) = *reinterpret_cast<const float4*>(rp1 + oe);
    *reinterpret_cast<float4*>(&w2[0]) = *reinterpret_cast<const float4*>(rp2 + oa);
    *reinterpret_cast<float4*>(&w2[4]) = *reinterpret_cast<const float4*>(rp2 + x0);
    *reinterpret_cast<float4*>(&w2[8]) = *reinterpret_cast<const float4*>(rp2 + oe);
    *reinterpret_cast<float4*>(&w3[0]) = *reinterpret_cast<const float4*>(rp3 + oa);
    *reinterpret_cast<float4*>(&w3[4]) = *reinterpret_cast<const float4*>(rp3 + x0);
    *reinterpret_cast<float4*>(&w3[8]) = *reinterpret_cast<const float4*>(rp3 + oe);

    if (r <= 8) {                       // dy=0 contribution, p = r
      const float* fbp = &ldsF[0][(r * DD) * XT + (xg << 2)];
#pragma unroll
      for (int o = 0; o < DD; ++o) {
        const float4 fo = *reinterpret_cast<const float4*>(fbp + o * XT);
        FMA16(a00, a01, a02, a03, fo, o)
      }
    }
    if (r >= 1) {                       // dy=1 contribution, p = r-1
      const float* fbp = &ldsF[1][((r - 1) * DD) * XT + (xg << 2)];
#pragma unroll
      for (int o = 0; o < DD; ++o) {
        const float4 fo = *reinterpret_cast<const float4*>(fbp + o * XT);
        FMA16(a10, a11, a12, a13, fo, o)
      }
    }

    rp0 += W_; rp1 += W_; rp2 += W_; rp3 += W_;
  }

  const float inv_c = 1.0f / (float)C_;
  float* ob0 = out + (size_t)b * C_ * HW + (size_t)y0 * W_ + x0;
  float* ob1 = ob0 + W_;
#define STORE4(PTR, CI, ACC)                                              \
  {                                                                       \
    float4 v;                                                             \
    v.x = ACC[0] * inv_c; v.y = ACC[1] * inv_c;                           \
    v.z = ACC[2] * inv_c; v.w = ACC[3] * inv_c;                           \
    *reinterpret_cast<float4*>(PTR + (size_t)(c0 + CI) * HW) = v;         \
  }
  STORE4(ob0, 0, a00)
  STORE4(ob0, 1, a01)
  STORE4(ob0, 2, a02)
  STORE4(ob0, 3, a03)
  STORE4(ob1, 0, a10)
  STORE4(ob1, 1, a11)
  STORE4(ob1, 2, a12)
  STORE4(ob1, 3, a13)
#undef STORE4
}

extern "C" void kernel_launch(void* const* d_in, const int* in_sizes, int n_in,
                              void* d_out, int out_size, void* d_ws, size_t ws_size,
                              hipStream_t stream) {
  const float* first  = (const float*)d_in[0];
  const float* second = (const float*)d_in[1];
  float* out = (float*)d_out;

  corr_transpose_kernel<<<dim3(NWG), 256, 0, stream>>>(first, second, out);
}

// Round 15
// 90.632 us; speedup vs baseline: 7.1991x; 1.2266x over previous
//
#include <hip/hip_runtime.h>

#define MD 4
#define DD 9          // 2*MD+1
#define KK 81         // DD*DD
#define B_ 4
#define C_ 128
#define H_ 192
#define W_ 192
#define HW (H_ * W_)
#define NWG 1152      // 96 y-pairs * 3 xt * 4 b  (all 128 ch per block)
#define PER_XCD (NWG / 8)

// out[b,c,y,x] = (1/C) * sum_{p,o} first[b,p*9+o,y,x] * second[b,c,y+p-4,x+o-4]
//
// Round 15 = round-13 kernel with launch_bounds(512, 2).
// r13's theory (share the 41.5KB weight slabs among 8 waves -> 24 waves/CU)
// was correct; its (512,6) second arg capped VGPR at 85 and the allocator
// spilled everything (VGPR 40, WRITE 1.6GB, 652us). Residency comes from
// runtime LDS/VGPR limits, not the launch-bounds floor: at ~72 VGPR and
// 41.5KB LDS, 3 blocks x 8 waves = 24 waves/CU (75%) vs r12's 12 (37.5%).
// (512,2) caps at 256 regs = the regime that produced r12's clean 72-VGPR
// codegen. Body identical to r12 (85.2us best): thread = 4x*4ch*2y, window
// loads reused across the y-pair (24:1 FMA:load), stage-masked x-edge
// weights, same accumulation order.
// Sentinels: VGPR 64-96 and WRITE == 73728 KB exactly (r13 spill alarm),
// Occupancy >= 50%, dur 50-68us.

#define FMA16(A0, A1, A2, A3, FO, O)                                   \
  A0[0] = fmaf(FO.x, w0[(O) + 0], A0[0]);                              \
  A0[1] = fmaf(FO.y, w0[(O) + 1], A0[1]);                              \
  A0[2] = fmaf(FO.z, w0[(O) + 2], A0[2]);                              \
  A0[3] = fmaf(FO.w, w0[(O) + 3], A0[3]);                              \
  A1[0] = fmaf(FO.x, w1[(O) + 0], A1[0]);                              \
  A1[1] = fmaf(FO.y, w1[(O) + 1], A1[1]);                              \
  A1[2] = fmaf(FO.z, w1[(O) + 2], A1[2]);                              \
  A1[3] = fmaf(FO.w, w1[(O) + 3], A1[3]);                              \
  A2[0] = fmaf(FO.x, w2[(O) + 0], A2[0]);                              \
  A2[1] = fmaf(FO.y, w2[(O) + 1], A2[1]);                              \
  A2[2] = fmaf(FO.z, w2[(O) + 2], A2[2]);                              \
  A2[3] = fmaf(FO.w, w2[(O) + 3], A2[3]);                              \
  A3[0] = fmaf(FO.x, w3[(O) + 0], A3[0]);                              \
  A3[1] = fmaf(FO.y, w3[(O) + 1], A3[1]);                              \
  A3[2] = fmaf(FO.z, w3[(O) + 2], A3[2]);                              \
  A3[3] = fmaf(FO.w, w3[(O) + 3], A3[3]);

__global__ __launch_bounds__(512, 2)
void corr_transpose_kernel(const float* __restrict__ first,
                           const float* __restrict__ second,
                           float* __restrict__ out) {
  __shared__ __align__(16) float ldsF[2][KK * 64];

  // bijective XCD swizzle (1152 % 8 == 0), y-pair-fastest within an XCD chunk
  const int lin = blockIdx.x;
  const int wid = (lin & 7) * PER_XCD + (lin >> 3);
  const int yp  = wid % 96;
  const int t   = wid / 96;          // 0..11
  const int xt0 = (t % 3) * 64;
  const int b   = t / 3;
  const int y0  = yp * 2;            // output rows y0, y0+1

  const int tid = threadIdx.x;

  // ---- stage first[b,:,y0+slab,xt0..+63] into 2 LDS slabs, edge-masked ----
  const bool edge = (xt0 != 64);     // block-uniform
#pragma unroll
  for (int slab = 0; slab < 2; ++slab) {
    const float* fbase =
        first + ((size_t)(b * KK) * H_ + (y0 + slab)) * (size_t)W_ + xt0;
    for (int idx = tid; idx < KK * 16; idx += 512) {
      const int k  = idx >> 4;
      const int xi = (idx & 15) << 2;
      float4 v = *reinterpret_cast<const float4*>(fbase + (size_t)k * HW + xi);
      if (edge) {
        const int o    = k % DD;
        const int base = xt0 + xi + o - MD;   // second-x for component 0
        if (base + 0 < 0 || base + 0 >= W_) v.x = 0.f;
        if (base + 1 < 0 || base + 1 >= W_) v.y = 0.f;
        if (base + 2 < 0 || base + 2 >= W_) v.z = 0.f;
        if (base + 3 < 0 || base + 3 >= W_) v.w = 0.f;
      }
      *reinterpret_cast<float4*>(&ldsF[slab][k * 64 + xi]) = v;
    }
  }

  const int xg = tid & 15;           // 16 x-groups (vec4)
  const int cg = tid >> 4;           // 0..31, 4 channels each -> 128 ch
  const int c0 = cg * 4;
  const int x0 = xt0 + xg * 4;

  // clamped window offsets; OOB float4s have zeroed weights in LDS
  const bool mA = (x0 != 0);
  const bool mE = (x0 + 8 <= W_);
  const int  oa = mA ? x0 - 4 : 0;
  const int  oe = mE ? x0 + 4 : W_ - 8;

  // row range: yy = y0-4+r, r in [r_lo, r_hi], yy within [0,191]
  const int r_lo = (y0 >= MD) ? 0 : (MD - y0);
  const int r_hi = (195 - y0 < 9) ? (195 - y0) : 9;

  const float* secB = second + (size_t)b * C_ * HW;
  const float* rp0 =
      secB + ((size_t)(c0 + 0) * H_ + (y0 - MD + r_lo)) * (size_t)W_;
  const float* rp1 = rp0 + HW;
  const float* rp2 = rp1 + HW;
  const float* rp3 = rp2 + HW;

  __syncthreads();

  float a00[4] = {0.f, 0.f, 0.f, 0.f};   // dy0, ci=0..3
  float a01[4] = {0.f, 0.f, 0.f, 0.f};
  float a02[4] = {0.f, 0.f, 0.f, 0.f};
  float a03[4] = {0.f, 0.f, 0.f, 0.f};
  float a10[4] = {0.f, 0.f, 0.f, 0.f};   // dy1
  float a11[4] = {0.f, 0.f, 0.f, 0.f};
  float a12[4] = {0.f, 0.f, 0.f, 0.f};
  float a13[4] = {0.f, 0.f, 0.f, 0.f};

  for (int r = r_lo; r <= r_hi; ++r) {
    // windows: second[c0+ci, yy, x0-4 .. x0+7] (12 floats each)
    float w0[12], w1[12], w2[12], w3[12];
    *reinterpret_cast<float4*>(&w0[0]) = *reinterpret_cast<const float4*>(rp0 + oa);
    *reinterpret_cast<float4*>(&w0[4]) = *reinterpret_cast<const float4*>(rp0 + x0);
    *reinterpret_cast<float4*>(&w0[8]) = *reinterpret_cast<const float4*>(rp0 + oe);
    *reinterpret_cast<float4*>(&w1[0]) = *reinterpret_cast<const float4*>(rp1 + oa);
    *reinterpret_cast<float4*>(&w1[4]) = *reinterpret_cast<const float4*>(rp1 + x0);
    *reinterpret_cast<float4*>(&w1[8]) = *reinterpret_cast<const float4*>(rp1 + oe);
    *reinterpret_cast<float4*>(&w2[0]) = *reinterpret_cast<const float4*>(rp2 + oa);
    *reinterpret_cast<float4*>(&w2[4]) = *reinterpret_cast<const float4*>(rp2 + x0);
    *reinterpret_cast<float4*>(&w2[8]) = *reinterpret_cast<const float4*>(rp2 + oe);
    *reinterpret_cast<float4*>(&w3[0]) = *reinterpret_cast<const float4*>(rp3 + oa);
    *reinterpret_cast<float4*>(&w3[4]) = *reinterpret_cast<const float4*>(rp3 + x0);
    *reinterpret_cast<float4*>(&w3[8]) = *reinterpret_cast<const float4*>(rp3 + oe);

    if (r <= 8) {                       // dy=0 contribution, p = r
      const float* fbp = &ldsF[0][(r * DD) * 64 + (xg << 2)];
#pragma unroll
      for (int o = 0; o < DD; ++o) {
        const float4 fo = *reinterpret_cast<const float4*>(fbp + o * 64);
        FMA16(a00, a01, a02, a03, fo, o)
      }
    }
    if (r >= 1) {                       // dy=1 contribution, p = r-1
      const float* fbp = &ldsF[1][((r - 1) * DD) * 64 + (xg << 2)];
#pragma unroll
      for (int o = 0; o < DD; ++o) {
        const float4 fo = *reinterpret_cast<const float4*>(fbp + o * 64);
        FMA16(a10, a11, a12, a13, fo, o)
      }
    }

    rp0 += W_; rp1 += W_; rp2 += W_; rp3 += W_;
  }

  const float inv_c = 1.0f / (float)C_;
  float* ob0 = out + (size_t)b * C_ * HW + (size_t)y0 * W_ + x0;
  float* ob1 = ob0 + W_;
#define STORE4(PTR, CI, ACC)                                              \
  {                                                                       \
    float4 v;                                                             \
    v.x = ACC[0] * inv_c; v.y = ACC[1] * inv_c;                           \
    v.z = ACC[2] * inv_c; v.w = ACC[3] * inv_c;                           \
    *reinterpret_cast<float4*>(PTR + (size_t)(c0 + CI) * HW) = v;         \
  }
  STORE4(ob0, 0, a00)
  STORE4(ob0, 1, a01)
  STORE4(ob0, 2, a02)
  STORE4(ob0, 3, a03)
  STORE4(ob1, 0, a10)
  STORE4(ob1, 1, a11)
  STORE4(ob1, 2, a12)
  STORE4(ob1, 3, a13)
#undef STORE4
}

extern "C" void kernel_launch(void* const* d_in, const int* in_sizes, int n_in,
                              void* d_out, int out_size, void* d_ws, size_t ws_size,
                              hipStream_t stream) {
  const float* first  = (const float*)d_in[0];
  const float* second = (const float*)d_in[1];
  float* out = (float*)d_out;

  corr_transpose_kernel<<<dim3(NWG), 512, 0, stream>>>(first, second, out);
}

// Round 16
// 85.820 us; speedup vs baseline: 7.6028x; 1.0561x over previous
//
#include <hip/hip_runtime.h>

#define MD 4
#define DD 9          // 2*MD+1
#define KK 81         // DD*DD
#define B_ 4
#define C_ 128
#define H_ 192
#define W_ 192
#define HW (H_ * W_)
#define NWG 2304      // 96 y-pairs * 3 xt * 2 chh * 4 b
#define PER_XCD (NWG / 8)

// out[b,c,y,x] = (1/C) * sum_{p,o} first[b,p*9+o,y,x] * second[b,c,y+p-4,x+o-4]
//
// Round 16 = round-12 kernel (85.2us best) + convoy-breaking stagger.
// Model fitting r12-r15: dur == SERIAL SUM of pipes (L1 29 + DS 29 + VALU 21
// ~= 85us) at ANY occupancy (12, 9, 6 waves/CU all ~85-111us). VALUBusy 27%
// == VALU's serial share. Cause: all co-resident waves run the identical
// barrier-free loop, start together, and fair round-robin arbitration at
// L1/DS keeps them PHASE-LOCKED (issue loads together -> wait together ->
// DS together -> FMA together). Per-iter wall = sum of pipe times, not max.
// Fix: stagger block start phases by ((lin>>3)&3) x ~576cyc s_sleep. Same-CU
// blocks share lin&7 (HW deals consecutive lin round-robin over XCDs) and
// differ in lin>>3 -> 3 resident blocks get 3 distinct phases. Cost <=0.7us.
// Body byte-identical to r12: thread = 4x*4ch*2y, window reuse across the
// y-pair, stage-masked x-edge weights, (256,2).
// Sentinels: VGPR 72, WRITE == 73728 KB, LDS 41472. Test: VALUBusy >= 40%.

#define FMA16(A0, A1, A2, A3, FO, O)                                   \
  A0[0] = fmaf(FO.x, w0[(O) + 0], A0[0]);                              \
  A0[1] = fmaf(FO.y, w0[(O) + 1], A0[1]);                              \
  A0[2] = fmaf(FO.z, w0[(O) + 2], A0[2]);                              \
  A0[3] = fmaf(FO.w, w0[(O) + 3], A0[3]);                              \
  A1[0] = fmaf(FO.x, w1[(O) + 0], A1[0]);                              \
  A1[1] = fmaf(FO.y, w1[(O) + 1], A1[1]);                              \
  A1[2] = fmaf(FO.z, w1[(O) + 2], A1[2]);                              \
  A1[3] = fmaf(FO.w, w1[(O) + 3], A1[3]);                              \
  A2[0] = fmaf(FO.x, w2[(O) + 0], A2[0]);                              \
  A2[1] = fmaf(FO.y, w2[(O) + 1], A2[1]);                              \
  A2[2] = fmaf(FO.z, w2[(O) + 2], A2[2]);                              \
  A2[3] = fmaf(FO.w, w2[(O) + 3], A2[3]);                              \
  A3[0] = fmaf(FO.x, w3[(O) + 0], A3[0]);                              \
  A3[1] = fmaf(FO.y, w3[(O) + 1], A3[1]);                              \
  A3[2] = fmaf(FO.z, w3[(O) + 2], A3[2]);                              \
  A3[3] = fmaf(FO.w, w3[(O) + 3], A3[3]);

__global__ __launch_bounds__(256, 2)
void corr_transpose_kernel(const float* __restrict__ first,
                           const float* __restrict__ second,
                           float* __restrict__ out) {
  __shared__ __align__(16) float ldsF[2][KK * 64];

  // bijective XCD swizzle (2304 % 8 == 0), y-pair-fastest within an XCD chunk
  const int lin = blockIdx.x;
  const int wid = (lin & 7) * PER_XCD + (lin >> 3);
  const int yp  = wid % 96;
  const int t   = wid / 96;          // 0..23
  const int chh = t & 1;
  const int xt0 = ((t >> 1) % 3) * 64;
  const int b   = t / 6;
  const int y0  = yp * 2;            // output rows y0, y0+1

  const int tid = threadIdx.x;

  // ---- stage first[b,:,y0+slab,xt0..+63] into 2 LDS slabs, edge-masked ----
  const bool edge = (xt0 != 64);     // block-uniform
#pragma unroll
  for (int slab = 0; slab < 2; ++slab) {
    const float* fbase =
        first + ((size_t)(b * KK) * H_ + (y0 + slab)) * (size_t)W_ + xt0;
    for (int idx = tid; idx < KK * 16; idx += 256) {
      const int k  = idx >> 4;
      const int xi = (idx & 15) << 2;
      float4 v = *reinterpret_cast<const float4*>(fbase + (size_t)k * HW + xi);
      if (edge) {
        const int o    = k % DD;
        const int base = xt0 + xi + o - MD;   // second-x for component 0
        if (base + 0 < 0 || base + 0 >= W_) v.x = 0.f;
        if (base + 1 < 0 || base + 1 >= W_) v.y = 0.f;
        if (base + 2 < 0 || base + 2 >= W_) v.z = 0.f;
        if (base + 3 < 0 || base + 3 >= W_) v.w = 0.f;
      }
      *reinterpret_cast<float4*>(&ldsF[slab][k * 64 + xi]) = v;
    }
  }

  const int xg = tid & 15;
  const int cg = tid >> 4;
  const int c0 = chh * 64 + cg * 4;
  const int x0 = xt0 + xg * 4;

  // clamped window offsets; OOB float4s have zeroed weights in LDS
  const bool mA = (x0 != 0);
  const bool mE = (x0 + 8 <= W_);
  const int  oa = mA ? x0 - 4 : 0;
  const int  oe = mE ? x0 + 4 : W_ - 8;

  // row range: yy = y0-4+r, r in [r_lo, r_hi], yy within [0,191]
  const int r_lo = (y0 >= MD) ? 0 : (MD - y0);
  const int r_hi = (195 - y0 < 9) ? (195 - y0) : 9;

  const float* secB = second + (size_t)b * C_ * HW;
  const float* rp0 =
      secB + ((size_t)(c0 + 0) * H_ + (y0 - MD + r_lo)) * (size_t)W_;
  const float* rp1 = rp0 + HW;
  const float* rp2 = rp1 + HW;
  const float* rp3 = rp2 + HW;

  __syncthreads();

  // ---- convoy breaker: stagger resident blocks by ~576-cycle quanta ----
  {
    const int phase = (lin >> 3) & 3;
    for (int s = 0; s < phase; ++s) __builtin_amdgcn_s_sleep(9);
  }

  float a00[4] = {0.f, 0.f, 0.f, 0.f};   // dy0, ci=0..3
  float a01[4] = {0.f, 0.f, 0.f, 0.f};
  float a02[4] = {0.f, 0.f, 0.f, 0.f};
  float a03[4] = {0.f, 0.f, 0.f, 0.f};
  float a10[4] = {0.f, 0.f, 0.f, 0.f};   // dy1
  float a11[4] = {0.f, 0.f, 0.f, 0.f};
  float a12[4] = {0.f, 0.f, 0.f, 0.f};
  float a13[4] = {0.f, 0.f, 0.f, 0.f};

  for (int r = r_lo; r <= r_hi; ++r) {
    // windows: second[c0+ci, yy, x0-4 .. x0+7] (12 floats each)
    float w0[12], w1[12], w2[12], w3[12];
    *reinterpret_cast<float4*>(&w0[0]) = *reinterpret_cast<const float4*>(rp0 + oa);
    *reinterpret_cast<float4*>(&w0[4]) = *reinterpret_cast<const float4*>(rp0 + x0);
    *reinterpret_cast<float4*>(&w0[8]) = *reinterpret_cast<const float4*>(rp0 + oe);
    *reinterpret_cast<float4*>(&w1[0]) = *reinterpret_cast<const float4*>(rp1 + oa);
    *reinterpret_cast<float4*>(&w1[4]) = *reinterpret_cast<const float4*>(rp1 + x0);
    *reinterpret_cast<float4*>(&w1[8]) = *reinterpret_cast<const float4*>(rp1 + oe);
    *reinterpret_cast<float4*>(&w2[0]) = *reinterpret_cast<const float4*>(rp2 + oa);
    *reinterpret_cast<float4*>(&w2[4]) = *reinterpret_cast<const float4*>(rp2 + x0);
    *reinterpret_cast<float4*>(&w2[8]) = *reinterpret_cast<const float4*>(rp2 + oe);
    *reinterpret_cast<float4*>(&w3[0]) = *reinterpret_cast<const float4*>(rp3 + oa);
    *reinterpret_cast<float4*>(&w3[4]) = *reinterpret_cast<const float4*>(rp3 + x0);
    *reinterpret_cast<float4*>(&w3[8]) = *reinterpret_cast<const float4*>(rp3 + oe);

    if (r <= 8) {                       // dy=0 contribution, p = r
      const float* fbp = &ldsF[0][(r * DD) * 64 + (xg << 2)];
#pragma unroll
      for (int o = 0; o < DD; ++o) {
        const float4 fo = *reinterpret_cast<const float4*>(fbp + o * 64);
        FMA16(a00, a01, a02, a03, fo, o)
      }
    }
    if (r >= 1) {                       // dy=1 contribution, p = r-1
      const float* fbp = &ldsF[1][((r - 1) * DD) * 64 + (xg << 2)];
#pragma unroll
      for (int o = 0; o < DD; ++o) {
        const float4 fo = *reinterpret_cast<const float4*>(fbp + o * 64);
        FMA16(a10, a11, a12, a13, fo, o)
      }
    }

    rp0 += W_; rp1 += W_; rp2 += W_; rp3 += W_;
  }

  const float inv_c = 1.0f / (float)C_;
  float* ob0 = out + (size_t)b * C_ * HW + (size_t)y0 * W_ + x0;
  float* ob1 = ob0 + W_;
#define STORE4(PTR, CI, ACC)                                              \
  {                                                                       \
    float4 v;                                                             \
    v.x = ACC[0] * inv_c; v.y = ACC[1] * inv_c;                           \
    v.z = ACC[2] * inv_c; v.w = ACC[3] * inv_c;                           \
    *reinterpret_cast<float4*>(PTR + (size_t)(c0 + CI) * HW) = v;         \
  }
  STORE4(ob0, 0, a00)
  STORE4(ob0, 1, a01)
  STORE4(ob0, 2, a02)
  STORE4(ob0, 3, a03)
  STORE4(ob1, 0, a10)
  STORE4(ob1, 1, a11)
  STORE4(ob1, 2, a12)
  STORE4(ob1, 3, a13)
#undef STORE4
}

extern "C" void kernel_launch(void* const* d_in, const int* in_sizes, int n_in,
                              void* d_out, int out_size, void* d_ws, size_t ws_size,
                              hipStream_t stream) {
  const float* first  = (const float*)d_in[0];
  const float* second = (const float*)d_in[1];
  float* out = (float*)d_out;

  corr_transpose_kernel<<<dim3(NWG), 256, 0, stream>>>(first, second, out);
}

// Round 17
// 81.850 us; speedup vs baseline: 7.9716x; 1.0485x over previous
//
#include <hip/hip_runtime.h>
#include <stdint.h>

#define MD 4
#define DD 9          // 2*MD+1
#define KK 81         // DD*DD
#define B_ 4
#define C_ 128
#define H_ 192
#define W_ 192
#define HW (H_ * W_)
#define NWG 2304      // 96 y-pairs * 3 xt * 2 chh * 4 b
#define PER_XCD (NWG / 8)

// out[b,c,y,x] = (1/C) * sum_{p,o} first[b,p*9+o,y,x] * second[b,c,y+p-4,x+o-4]
//
// Round 17 = round-12 body + MLP pinned at 12 via inline-asm buffer loads.
// Surviving model after r12-r16: wall == serial sum of pipe times per wave at
// ANY occupancy/phase (85us; stagger r16 changed nothing). Cause: at VGPR=72
// the allocator batches the 12 window loads 2-3x per iter -> multiple
// congested-L2 round trips exposed per iter; 3 waves/SIMD can't cover.
// Fix: 12 volatile `buffer_load_dwordx4` (one SRSRC over `second`, 32-bit
// voffsets) + ONE `s_waitcnt vmcnt(0)` asm holding all 12 f32x4 as "+v".
// Volatile order + data ties force 48 data regs live -> ~110 VGPR under the
// (256,2)=128 cap (r2-proven grant), one latency exposure per iter, HW MLP=12.
// LDS fo reads stay compiler-scheduled (hoist into the vmem wait window).
// Body/numerics identical to r12 (absmax 9.8e-4).
// Sentinels: VGPR 100-128 (<=80 -> pin failed), WRITE == 73728 KB exactly
// (spill alarm), VALUBusy >= 45%, dur 50-65us.

typedef float        f32x4 __attribute__((ext_vector_type(4)));
typedef unsigned int u32x4 __attribute__((ext_vector_type(4)));

#define FMA16(A0, A1, A2, A3, FO, O)                                   \
  A0[0] = fmaf(FO.x, w0[(O) + 0], A0[0]);                              \
  A0[1] = fmaf(FO.y, w0[(O) + 1], A0[1]);                              \
  A0[2] = fmaf(FO.z, w0[(O) + 2], A0[2]);                              \
  A0[3] = fmaf(FO.w, w0[(O) + 3], A0[3]);                              \
  A1[0] = fmaf(FO.x, w1[(O) + 0], A1[0]);                              \
  A1[1] = fmaf(FO.y, w1[(O) + 1], A1[1]);                              \
  A1[2] = fmaf(FO.z, w1[(O) + 2], A1[2]);                              \
  A1[3] = fmaf(FO.w, w1[(O) + 3], A1[3]);                              \
  A2[0] = fmaf(FO.x, w2[(O) + 0], A2[0]);                              \
  A2[1] = fmaf(FO.y, w2[(O) + 1], A2[1]);                              \
  A2[2] = fmaf(FO.z, w2[(O) + 2], A2[2]);                              \
  A2[3] = fmaf(FO.w, w2[(O) + 3], A2[3]);                              \
  A3[0] = fmaf(FO.x, w3[(O) + 0], A3[0]);                              \
  A3[1] = fmaf(FO.y, w3[(O) + 1], A3[1]);                              \
  A3[2] = fmaf(FO.z, w3[(O) + 2], A3[2]);                              \
  A3[3] = fmaf(FO.w, w3[(O) + 3], A3[3]);

#define BLD(dst, off)                                                  \
  asm volatile("buffer_load_dwordx4 %0, %1, %2, 0 offen"               \
               : "=v"(dst) : "v"(off), "s"(srsrc))

__global__ __launch_bounds__(256, 2)
void corr_transpose_kernel(const float* __restrict__ first,
                           const float* __restrict__ second,
                           float* __restrict__ out) {
  __shared__ __align__(16) float ldsF[2][KK * 64];

  // bijective XCD swizzle (2304 % 8 == 0), y-pair-fastest within an XCD chunk
  const int lin = blockIdx.x;
  const int wid = (lin & 7) * PER_XCD + (lin >> 3);
  const int yp  = wid % 96;
  const int t   = wid / 96;          // 0..23
  const int chh = t & 1;
  const int xt0 = ((t >> 1) % 3) * 64;
  const int b   = t / 6;
  const int y0  = yp * 2;            // output rows y0, y0+1

  const int tid = threadIdx.x;

  // ---- stage first[b,:,y0+slab,xt0..+63] into 2 LDS slabs, edge-masked ----
  const bool edge = (xt0 != 64);     // block-uniform
#pragma unroll
  for (int slab = 0; slab < 2; ++slab) {
    const float* fbase =
        first + ((size_t)(b * KK) * H_ + (y0 + slab)) * (size_t)W_ + xt0;
    for (int idx = tid; idx < KK * 16; idx += 256) {
      const int k  = idx >> 4;
      const int xi = (idx & 15) << 2;
      float4 v = *reinterpret_cast<const float4*>(fbase + (size_t)k * HW + xi);
      if (edge) {
        const int o    = k % DD;
        const int base = xt0 + xi + o - MD;   // second-x for component 0
        if (base + 0 < 0 || base + 0 >= W_) v.x = 0.f;
        if (base + 1 < 0 || base + 1 >= W_) v.y = 0.f;
        if (base + 2 < 0 || base + 2 >= W_) v.z = 0.f;
        if (base + 3 < 0 || base + 3 >= W_) v.w = 0.f;
      }
      *reinterpret_cast<float4*>(&ldsF[slab][k * 64 + xi]) = v;
    }
  }

  const int xg = tid & 15;
  const int cg = tid >> 4;
  const int c0 = chh * 64 + cg * 4;
  const int x0 = xt0 + xg * 4;

  // clamped window offsets; OOB float4s have zeroed weights in LDS
  const bool mA = (x0 != 0);
  const bool mE = (x0 + 8 <= W_);
  const int  oa = mA ? x0 - 4 : 0;
  const int  oe = mE ? x0 + 4 : W_ - 8;

  // row range: yy = y0-4+r, r in [r_lo, r_hi], yy within [0,191]
  const int r_lo = (y0 >= MD) ? 0 : (MD - y0);
  const int r_hi = (195 - y0 < 9) ? (195 - y0) : 9;
  const int yy0  = y0 - MD + r_lo;

  // ---- SRSRC over second[b] + 12 x 32-bit byte voffsets ----
  const uint64_t secAddr = (uint64_t)(second + (size_t)b * C_ * HW);
  u32x4 srsrc;
  srsrc.x = (unsigned int)(secAddr & 0xFFFFFFFFu);
  srsrc.y = (unsigned int)(secAddr >> 32);     // stride=0
  srsrc.z = 0xFFFFFFFFu;                       // num_records: disabled
  srsrc.w = 0x00020000u;                       // raw dword access

  unsigned int rb0 = (unsigned int)((((c0 + 0) * H_ + yy0) * W_) * 4);
  unsigned int rb1 = rb0 + HW * 4;
  unsigned int rb2 = rb1 + HW * 4;
  unsigned int rb3 = rb2 + HW * 4;
  unsigned int offA0 = rb0 + oa * 4, offM0 = rb0 + x0 * 4, offE0 = rb0 + oe * 4;
  unsigned int offA1 = rb1 + oa * 4, offM1 = rb1 + x0 * 4, offE1 = rb1 + oe * 4;
  unsigned int offA2 = rb2 + oa * 4, offM2 = rb2 + x0 * 4, offE2 = rb2 + oe * 4;
  unsigned int offA3 = rb3 + oa * 4, offM3 = rb3 + x0 * 4, offE3 = rb3 + oe * 4;

  __syncthreads();

  float a00[4] = {0.f, 0.f, 0.f, 0.f};   // dy0, ci=0..3
  float a01[4] = {0.f, 0.f, 0.f, 0.f};
  float a02[4] = {0.f, 0.f, 0.f, 0.f};
  float a03[4] = {0.f, 0.f, 0.f, 0.f};
  float a10[4] = {0.f, 0.f, 0.f, 0.f};   // dy1
  float a11[4] = {0.f, 0.f, 0.f, 0.f};
  float a12[4] = {0.f, 0.f, 0.f, 0.f};
  float a13[4] = {0.f, 0.f, 0.f, 0.f};

  for (int r = r_lo; r <= r_hi; ++r) {
    // ---- 12 loads in flight, ONE wait: pinned MLP=12 ----
    f32x4 vA0, vM0, vE0, vA1, vM1, vE1, vA2, vM2, vE2, vA3, vM3, vE3;
    BLD(vA0, offA0); BLD(vM0, offM0); BLD(vE0, offE0);
    BLD(vA1, offA1); BLD(vM1, offM1); BLD(vE1, offE1);
    BLD(vA2, offA2); BLD(vM2, offM2); BLD(vE2, offE2);
    BLD(vA3, offA3); BLD(vM3, offM3); BLD(vE3, offE3);
    asm volatile("s_waitcnt vmcnt(0)"
                 : "+v"(vA0), "+v"(vM0), "+v"(vE0),
                   "+v"(vA1), "+v"(vM1), "+v"(vE1),
                   "+v"(vA2), "+v"(vM2), "+v"(vE2),
                   "+v"(vA3), "+v"(vM3), "+v"(vE3));

    float w0[12], w1[12], w2[12], w3[12];
    *reinterpret_cast<f32x4*>(&w0[0]) = vA0;
    *reinterpret_cast<f32x4*>(&w0[4]) = vM0;
    *reinterpret_cast<f32x4*>(&w0[8]) = vE0;
    *reinterpret_cast<f32x4*>(&w1[0]) = vA1;
    *reinterpret_cast<f32x4*>(&w1[4]) = vM1;
    *reinterpret_cast<f32x4*>(&w1[8]) = vE1;
    *reinterpret_cast<f32x4*>(&w2[0]) = vA2;
    *reinterpret_cast<f32x4*>(&w2[4]) = vM2;
    *reinterpret_cast<f32x4*>(&w2[8]) = vE2;
    *reinterpret_cast<f32x4*>(&w3[0]) = vA3;
    *reinterpret_cast<f32x4*>(&w3[4]) = vM3;
    *reinterpret_cast<f32x4*>(&w3[8]) = vE3;

    if (r <= 8) {                       // dy=0 contribution, p = r
      const float* fbp = &ldsF[0][(r * DD) * 64 + (xg << 2)];
#pragma unroll
      for (int o = 0; o < DD; ++o) {
        const float4 fo = *reinterpret_cast<const float4*>(fbp + o * 64);
        FMA16(a00, a01, a02, a03, fo, o)
      }
    }
    if (r >= 1) {                       // dy=1 contribution, p = r-1
      const float* fbp = &ldsF[1][((r - 1) * DD) * 64 + (xg << 2)];
#pragma unroll
      for (int o = 0; o < DD; ++o) {
        const float4 fo = *reinterpret_cast<const float4*>(fbp + o * 64);
        FMA16(a10, a11, a12, a13, fo, o)
      }
    }

    offA0 += W_ * 4; offM0 += W_ * 4; offE0 += W_ * 4;
    offA1 += W_ * 4; offM1 += W_ * 4; offE1 += W_ * 4;
    offA2 += W_ * 4; offM2 += W_ * 4; offE2 += W_ * 4;
    offA3 += W_ * 4; offM3 += W_ * 4; offE3 += W_ * 4;
  }

  const float inv_c = 1.0f / (float)C_;
  float* ob0 = out + (size_t)b * C_ * HW + (size_t)y0 * W_ + x0;
  float* ob1 = ob0 + W_;
#define STORE4(PTR, CI, ACC)                                              \
  {                                                                       \
    float4 v;                                                             \
    v.x = ACC[0] * inv_c; v.y = ACC[1] * inv_c;                           \
    v.z = ACC[2] * inv_c; v.w = ACC[3] * inv_c;                           \
    *reinterpret_cast<float4*>(PTR + (size_t)(c0 + CI) * HW) = v;         \
  }
  STORE4(ob0, 0, a00)
  STORE4(ob0, 1, a01)
  STORE4(ob0, 2, a02)
  STORE4(ob0, 3, a03)
  STORE4(ob1, 0, a10)
  STORE4(ob1, 1, a11)
  STORE4(ob1, 2, a12)
  STORE4(ob1, 3, a13)
#undef STORE4
}

extern "C" void kernel_launch(void* const* d_in, const int* in_sizes, int n_in,
                              void* d_out, int out_size, void* d_ws, size_t ws_size,
                              hipStream_t stream) {
  const float* first  = (const float*)d_in[0];
  const float* second = (const float*)d_in[1];
  float* out = (float*)d_out;

  corr_transpose_kernel<<<dim3(NWG), 256, 0, stream>>>(first, second, out);
}